// Round 4
// baseline (306.961 us; speedup 1.0000x reference)
//
#include <hip/hip_runtime.h>
#include <math.h>

// Problem constants: B=4096, T=200, D=64
#define TT 200
#define MTS 72   // Mt row stride in bf16 elems (144 B rows: 16B-aligned)

typedef __attribute__((ext_vector_type(8))) short bf16x8;  // 8 bf16 = 4 VGPRs
typedef __attribute__((ext_vector_type(4))) float f32x4;

union BF8 { bf16x8 v; unsigned u[4]; };

__device__ __forceinline__ float sigmoidf_(float x) {
    return 1.0f / (1.0f + __expf(-x));
}
// packed f32->bf16 RNE convert (1 instr for 2 values)
__device__ __forceinline__ unsigned cvtpk(float a, float b) {
    unsigned r;
    asm("v_cvt_pk_bf16_f32 %0, %1, %2" : "=v"(r) : "v"(a), "v"(b));
    return r;
}
// scalar bf16 RNE (used only in the once-per-row W1 fold)
__device__ __forceinline__ short f2bf(float x) {
    unsigned u = __float_as_uint(x);
    u += 0x7fff + ((u >> 16) & 1);
    return (short)(u >> 16);
}
__device__ __forceinline__ float bf2f(short s) {
    return __uint_as_float(((unsigned)(unsigned short)s) << 16);
}

// One wave = one batch row at a time; rows distributed DYNAMICALLY:
// wave g starts with static row (dynBase + g), then pulls rows [0, dynBase)
// from a global atomic counter (load-balances the random keys_length).
// Single pass over keys, tiles trimmed to ceil(len/16), exact-len predicated
// loads, 2-deep prefetch, fixed-bound softmax, zero block barriers.
__global__ __launch_bounds__(256, 2) void din_attn_flash(
    const float* __restrict__ queries,     // [B,64]
    const float* __restrict__ keys,        // [B,200,64]
    const int*   __restrict__ keys_length, // [B]
    const float* __restrict__ W1,          // [256,16]
    const float* __restrict__ b1,          // [16]
    const float* __restrict__ W2,          // [16,8]
    const float* __restrict__ b2,          // [8]
    const float* __restrict__ W3,          // [8,1]
    const float* __restrict__ b3,          // [1]
    const float* __restrict__ W4,          // [64,64]
    const float* __restrict__ b4,          // [64]
    float* __restrict__ out,               // [B,64]
    int Bn, int dynBase, int* __restrict__ cnt)
{
    __shared__ __align__(16) short MtHi[4][16 * MTS];   // per-wave folded W1^T hi
    __shared__ __align__(16) short MtLo[4][16 * MTS];   // per-wave folded W1^T lo
    __shared__ __align__(16) float vS[4][64];           // per-wave weighted key sum

    const int tid  = threadIdx.x;
    const int w    = tid >> 6;
    const int lane = tid & 63;
    const int m16  = lane & 15;
    const int quad = lane >> 4;
    const int gwid = blockIdx.x * 4 + w;

    // ======== row-independent setup (once per wave) ========
    // layer-2 A-frag: W2^T in scrambled-k order.
    // k-slot quad*8+j (j<4) carries h = quad*4+j; slots j>=4 zero.
    BF8 a2;
    {
        float w2f[4];
        #pragma unroll
        for (int j = 0; j < 4; j++)
            w2f[j] = (m16 < 8) ? W2[(quad * 4 + j) * 8 + m16] : 0.0f;
        a2.u[0] = cvtpk(w2f[0], w2f[1]);
        a2.u[1] = cvtpk(w2f[2], w2f[3]);
        a2.u[2] = 0u;
        a2.u[3] = 0u;
    }
    const float4 b2a = *(const float4*)(b2);
    const float4 b2b = *(const float4*)(b2 + 4);
    const float4 w3a = *(const float4*)(W3);
    const float4 w3b = *(const float4*)(W3 + 4);
    const float  b3v = b3[0];
    // per-lane layer-3 coefs for k = quad*4 + r (zero for pad quads 2,3)
    const float b2k0 = quad == 0 ? b2a.x : (quad == 1 ? b2b.x : 0.f);
    const float b2k1 = quad == 0 ? b2a.y : (quad == 1 ? b2b.y : 0.f);
    const float b2k2 = quad == 0 ? b2a.z : (quad == 1 ? b2b.z : 0.f);
    const float b2k3 = quad == 0 ? b2a.w : (quad == 1 ? b2b.w : 0.f);
    const float w3k0 = quad == 0 ? w3a.x : (quad == 1 ? w3b.x : 0.f);
    const float w3k1 = quad == 0 ? w3a.y : (quad == 1 ? w3b.y : 0.f);
    const float w3k2 = quad == 0 ? w3a.z : (quad == 1 ? w3b.z : 0.f);
    const float w3k3 = quad == 0 ? w3a.w : (quad == 1 ? w3b.w : 0.f);
    // fixed softmax shift: |sc| <= 0.125*(|b3| + sum|W3|)
    const float M = 0.125f * (fabsf(b3v)
                  + fabsf(w3a.x) + fabsf(w3a.y) + fabsf(w3a.z) + fabsf(w3a.w)
                  + fabsf(w3b.x) + fabsf(w3b.y) + fabsf(w3b.z) + fabsf(w3b.w));

    // ======== row loop: static row first, then atomic-dynamic rows ========
    int row = dynBase + gwid;
    if (row >= Bn) row = -1;

    while (row >= 0) {
        const int b = row;
        const int len = __builtin_amdgcn_readfirstlane(keys_length[b]);
        const float* kb = keys + (size_t)b * (TT * 64);

        // ---- fold W1: lane = (d2 = lane>>2 in 0..15, hg = lane&3) ----
        float cp0 = 0.f, cp1 = 0.f, cp2 = 0.f, cp3 = 0.f;
        {
            const int d2 = lane >> 2;
            const int hg = lane & 3;
            const float4* W1v = (const float4*)W1;   // [256][4] of float4
            #pragma unroll
            for (int dg = 0; dg < 4; dg++) {
                const int d = dg * 16 + d2;
                const float q = queries[b * 64 + d];
                float4 a  = W1v[(0   + d) * 4 + hg];
                float4 bb = W1v[(64  + d) * 4 + hg];
                float4 cc = W1v[(128 + d) * 4 + hg];
                float4 dd = W1v[(192 + d) * 4 + hg];
                float mv0 = bb.x - cc.x + q * dd.x;
                float mv1 = bb.y - cc.y + q * dd.y;
                float mv2 = bb.z - cc.z + q * dd.z;
                float mv3 = bb.w - cc.w + q * dd.w;
                cp0 += q * (a.x + cc.x);
                cp1 += q * (a.y + cc.y);
                cp2 += q * (a.z + cc.z);
                cp3 += q * (a.w + cc.w);
                const int hb = hg * 4;
                short h0 = f2bf(mv0), h1 = f2bf(mv1), h2 = f2bf(mv2), h3 = f2bf(mv3);
                MtHi[w][(hb + 0) * MTS + d] = h0;
                MtHi[w][(hb + 1) * MTS + d] = h1;
                MtHi[w][(hb + 2) * MTS + d] = h2;
                MtHi[w][(hb + 3) * MTS + d] = h3;
                MtLo[w][(hb + 0) * MTS + d] = f2bf(mv0 - bf2f(h0));
                MtLo[w][(hb + 1) * MTS + d] = f2bf(mv1 - bf2f(h1));
                MtLo[w][(hb + 2) * MTS + d] = f2bf(mv2 - bf2f(h2));
                MtLo[w][(hb + 3) * MTS + d] = f2bf(mv3 - bf2f(h3));
            }
            #pragma unroll
            for (int mask = 4; mask <= 32; mask <<= 1) {
                cp0 += __shfl_xor(cp0, mask, 64);
                cp1 += __shfl_xor(cp1, mask, 64);
                cp2 += __shfl_xor(cp2, mask, 64);
                cp3 += __shfl_xor(cp3, mask, 64);
            }
        }
        float cv4[4];
        cv4[0] = __shfl(cp0, quad, 64) + b1[quad * 4 + 0];
        cv4[1] = __shfl(cp1, quad, 64) + b1[quad * 4 + 1];
        cv4[2] = __shfl(cp2, quad, 64) + b1[quad * 4 + 2];
        cv4[3] = __shfl(cp3, quad, 64) + b1[quad * 4 + 3];

        // same-wave LDS write -> read (HW DS ops in-order per wave)
        asm volatile("" ::: "memory");
        __builtin_amdgcn_wave_barrier();

        // scorer A-frags (Mt): A[row=h=m16][k=d=quad*8+j]
        const int bb0 = m16 * MTS + quad * 8;
        const bf16x8 Bh0 = *(const bf16x8*)&MtHi[w][bb0];
        const bf16x8 Bh1 = *(const bf16x8*)&MtHi[w][bb0 + 32];
        const bf16x8 Bl0 = *(const bf16x8*)&MtLo[w][bb0];
        const bf16x8 Bl1 = *(const bf16x8*)&MtLo[w][bb0 + 32];

        // len==0: all positions masked in ref -> uniform softmax; sc=0.
        const int lenEff = (len == 0) ? TT : len;
        const int ntiles = (lenEff + 15) >> 4;

        float ssum = 0.0f;
        float o[16];
        #pragma unroll
        for (int j = 0; j < 16; j++) o[j] = 0.0f;

        const float4 z4 = {0.f, 0.f, 0.f, 0.f};
        #define LOADT(TL, A0, A1, A2, A3)                                   \
            { const int t_ = (TL) * 16 + m16;                               \
              if (t_ < lenEff) {                                            \
                  const float* p_ = kb + t_ * 64 + quad * 8;                \
                  A0 = *(const float4*)(p_);                                \
                  A1 = *(const float4*)(p_ + 4);                            \
                  A2 = *(const float4*)(p_ + 32);                           \
                  A3 = *(const float4*)(p_ + 36);                           \
              } else { A0 = z4; A1 = z4; A2 = z4; A3 = z4; } }

        float4 c0, c1, c2, c3, n0, n1, n2, n3;
        LOADT(0, c0, c1, c2, c3);
        LOADT(1, n0, n1, n2, n3);

        for (int tile = 0; tile < ntiles; tile++) {
            float4 m0, m1, m2, m3;
            LOADT(tile + 2, m0, m1, m2, m3);

            // keys -> bf16 (packed converts)
            BF8 ah0, ah1;
            ah0.u[0] = cvtpk(c0.x, c0.y);  ah0.u[1] = cvtpk(c0.z, c0.w);
            ah0.u[2] = cvtpk(c1.x, c1.y);  ah0.u[3] = cvtpk(c1.z, c1.w);
            ah1.u[0] = cvtpk(c2.x, c2.y);  ah1.u[1] = cvtpk(c2.z, c2.w);
            ah1.u[2] = cvtpk(c3.x, c3.y);  ah1.u[3] = cvtpk(c3.z, c3.w);

            // layer 1: D[h][t], lane holds t=m16, h=quad*4+r
            f32x4 acc = {0.f, 0.f, 0.f, 0.f};
            acc = __builtin_amdgcn_mfma_f32_16x16x32_bf16(Bh0, ah0.v, acc, 0, 0, 0);
            acc = __builtin_amdgcn_mfma_f32_16x16x32_bf16(Bl0, ah0.v, acc, 0, 0, 0);
            acc = __builtin_amdgcn_mfma_f32_16x16x32_bf16(Bh1, ah1.v, acc, 0, 0, 0);
            acc = __builtin_amdgcn_mfma_f32_16x16x32_bf16(Bl1, ah1.v, acc, 0, 0, 0);

            // sigmoid + pack h1 into scrambled-k B-frag (slots j>=4 zero)
            const float h10 = sigmoidf_(acc[0] + cv4[0]);
            const float h11 = sigmoidf_(acc[1] + cv4[1]);
            const float h12 = sigmoidf_(acc[2] + cv4[2]);
            const float h13 = sigmoidf_(acc[3] + cv4[3]);
            BF8 hb;
            hb.u[0] = cvtpk(h10, h11);
            hb.u[1] = cvtpk(h12, h13);
            hb.u[2] = 0u;
            hb.u[3] = 0u;

            // layer 2: D2[k][t]; lane holds k=quad*4+r
            f32x4 acc2 = {0.f, 0.f, 0.f, 0.f};
            acc2 = __builtin_amdgcn_mfma_f32_16x16x32_bf16(a2.v, hb.v, acc2, 0, 0, 0);

            // layer 3 partial over this lane's 4 k's, then cross-quad reduce
            float s3p;
            s3p = sigmoidf_(acc2[0] + b2k0) * w3k0;
            s3p = fmaf(sigmoidf_(acc2[1] + b2k1), w3k1, s3p);
            s3p = fmaf(sigmoidf_(acc2[2] + b2k2), w3k2, s3p);
            s3p = fmaf(sigmoidf_(acc2[3] + b2k3), w3k3, s3p);
            s3p += __shfl_xor(s3p, 16, 64);
            s3p += __shfl_xor(s3p, 32, 64);

            const int tg = tile * 16 + m16;
            float sc = (len == 0) ? 0.0f : (s3p + b3v) * 0.125f;  // / sqrt(64)
            if (tg >= lenEff) sc = -1.0e30f;                       // -> exp == 0
            const float p = __expf(sc - M);                        // <= 1

            ssum += p;
            o[0]  = fmaf(p, c0.x, o[0]);
            o[1]  = fmaf(p, c0.y, o[1]);
            o[2]  = fmaf(p, c0.z, o[2]);
            o[3]  = fmaf(p, c0.w, o[3]);
            o[4]  = fmaf(p, c1.x, o[4]);
            o[5]  = fmaf(p, c1.y, o[5]);
            o[6]  = fmaf(p, c1.z, o[6]);
            o[7]  = fmaf(p, c1.w, o[7]);
            o[8]  = fmaf(p, c2.x, o[8]);
            o[9]  = fmaf(p, c2.y, o[9]);
            o[10] = fmaf(p, c2.z, o[10]);
            o[11] = fmaf(p, c2.w, o[11]);
            o[12] = fmaf(p, c3.x, o[12]);
            o[13] = fmaf(p, c3.y, o[13]);
            o[14] = fmaf(p, c3.z, o[14]);
            o[15] = fmaf(p, c3.w, o[15]);

            c0 = n0; c1 = n1; c2 = n2; c3 = n3;
            n0 = m0; n1 = m1; n2 = m2; n3 = m3;
        }
        #undef LOADT

        // ---- final cross-t reduction (over m16 lanes) ----
        #pragma unroll
        for (int mask = 1; mask <= 8; mask <<= 1) {
            ssum += __shfl_xor(ssum, mask, 64);
            #pragma unroll
            for (int j = 0; j < 16; j++) o[j] += __shfl_xor(o[j], mask, 64);
        }
        const float inv = 1.0f / ssum;
        if (m16 == 0) {
            #pragma unroll
            for (int j = 0; j < 8; j++) vS[w][quad * 8 + j]      = o[j] * inv;
            #pragma unroll
            for (int j = 0; j < 8; j++) vS[w][32 + quad * 8 + j] = o[8 + j] * inv;
        }
        asm volatile("" ::: "memory");
        __builtin_amdgcn_wave_barrier();

        // ---- out[i=lane] = b4[i] + sum_d v[d] * W4[d][i] (W4 L2-hot) ----
        float po = b4[lane];
        const float4* vS4 = (const float4*)&vS[w][0];
        #pragma unroll 4
        for (int d0 = 0; d0 < 16; d0++) {
            const float4 vv = vS4[d0];
            const float* w4p = W4 + d0 * 256 + lane;
            po = fmaf(vv.x, w4p[0],   po);
            po = fmaf(vv.y, w4p[64],  po);
            po = fmaf(vv.z, w4p[128], po);
            po = fmaf(vv.w, w4p[192], po);
        }
        out[(size_t)b * 64 + lane] = po;

        // ---- grab next row (dynamic range [0, dynBase)) ----
        if (cnt == nullptr) break;
        int r = 0;
        if (lane == 0) r = atomicAdd(cnt, 1);
        r = __shfl(r, 0, 64);
        row = (r < dynBase) ? r : -1;
    }
}

extern "C" void kernel_launch(void* const* d_in, const int* in_sizes, int n_in,
                              void* d_out, int out_size, void* d_ws, size_t ws_size,
                              hipStream_t stream) {
    const float* queries     = (const float*)d_in[0];
    const float* keys        = (const float*)d_in[1];
    const int*   keys_length = (const int*)  d_in[2];
    const float* W1 = (const float*)d_in[3];
    const float* b1 = (const float*)d_in[4];
    const float* W2 = (const float*)d_in[5];
    const float* b2 = (const float*)d_in[6];
    const float* W3 = (const float*)d_in[7];
    const float* b3 = (const float*)d_in[8];
    const float* W4 = (const float*)d_in[9];
    const float* b4 = (const float*)d_in[10];
    float* out = (float*)d_out;

    const int Bn = in_sizes[2];   // 4096
    int* cnt = nullptr;
    int blocks, dynBase;
    if (ws_size >= sizeof(int) && Bn > 2048) {
        // 2048 waves: each takes 1 static row (dynBase..Bn), then pulls
        // rows [0, dynBase) from the atomic counter for load balance.
        blocks  = 512;
        dynBase = Bn - 2048;
        cnt     = (int*)d_ws;
        hipMemsetAsync(cnt, 0, sizeof(int), stream);
    } else {
        blocks  = (Bn + 3) >> 2;   // pure static: 1 row per wave
        dynBase = 0;
    }
    din_attn_flash<<<blocks, 256, 0, stream>>>(
        queries, keys, keys_length, W1, b1, W2, b2, W3, b3, W4, b4, out,
        Bn, dynBase, cnt);
}

// Round 6
// 289.077 us; speedup vs baseline: 1.0619x; 1.0619x over previous
//
#include <hip/hip_runtime.h>
#include <math.h>

// Problem constants: B=4096, T=200, D=64
#define TT 200
#define MTS 72   // Mt row stride in bf16 elems (144 B rows: 16B-aligned)

typedef __attribute__((ext_vector_type(8))) short bf16x8;  // 8 bf16 = 4 VGPRs
typedef __attribute__((ext_vector_type(4))) float f32x4;
typedef __attribute__((ext_vector_type(4))) float fv4;     // native vec for builtins

union BF8 { bf16x8 v; unsigned u[4]; };

__device__ __forceinline__ float sigmoidf_(float x) {
    return 1.0f / (1.0f + __expf(-x));
}
// packed f32->bf16 RNE convert (1 instr for 2 values)
__device__ __forceinline__ unsigned cvtpk(float a, float b) {
    unsigned r;
    asm("v_cvt_pk_bf16_f32 %0, %1, %2" : "=v"(r) : "v"(a), "v"(b));
    return r;
}
// scalar bf16 RNE (used only in the once-per-row W1 fold)
__device__ __forceinline__ short f2bf(float x) {
    unsigned u = __float_as_uint(x);
    u += 0x7fff + ((u >> 16) & 1);
    return (short)(u >> 16);
}
__device__ __forceinline__ float bf2f(short s) {
    return __uint_as_float(((unsigned)(unsigned short)s) << 16);
}
// streaming (non-temporal) float4 load: keys are read exactly once
__device__ __forceinline__ float4 ldnt4(const float* p) {
    fv4 t = __builtin_nontemporal_load((const fv4*)p);
    float4 r;
    r.x = t[0]; r.y = t[1]; r.z = t[2]; r.w = t[3];
    return r;
}

// One wave = one batch row; 4 waves (rows) per 256-thread block; static grid.
// Tile-0/1 key loads issue at kernel entry (unpredicated, before len arrives)
// so HBM latency overlaps the W1 fold. Single pass over keys, tiles trimmed
// to ceil(len/16), predicated loads from tile 2 on, 2-deep prefetch,
// fixed-bound softmax, zero block barriers, non-temporal key loads.
__global__ __launch_bounds__(256, 4) void din_attn_flash(
    const float* __restrict__ queries,     // [B,64]
    const float* __restrict__ keys,        // [B,200,64]
    const int*   __restrict__ keys_length, // [B]
    const float* __restrict__ W1,          // [256,16]
    const float* __restrict__ b1,          // [16]
    const float* __restrict__ W2,          // [16,8]
    const float* __restrict__ b2,          // [8]
    const float* __restrict__ W3,          // [8,1]
    const float* __restrict__ b3,          // [1]
    const float* __restrict__ W4,          // [64,64]
    const float* __restrict__ b4,          // [64]
    float* __restrict__ out,               // [B,64]
    int Bn)
{
    __shared__ __align__(16) short MtHi[4][16 * MTS];   // per-wave folded W1^T hi
    __shared__ __align__(16) short MtLo[4][16 * MTS];   // per-wave folded W1^T lo
    __shared__ __align__(16) float vS[4][64];           // per-wave weighted key sum

    const int tid  = threadIdx.x;
    const int w    = tid >> 6;
    const int lane = tid & 63;
    const int m16  = lane & 15;
    const int quad = lane >> 4;

    const int b = blockIdx.x * 4 + w;
    if (b >= Bn) return;
    const float* kb = keys + (size_t)b * (TT * 64);

    // ---- issue tile0/tile1 key loads NOW (t = m16, 16+m16 always < 200).
    // Rows past len are real floats; their p is exactly 0, so contributions
    // vanish. This overlaps key HBM latency with the whole W1 fold below.
    const float* kp0 = kb + m16 * 64 + quad * 8;
    float4 c0 = ldnt4(kp0);
    float4 c1 = ldnt4(kp0 + 4);
    float4 c2 = ldnt4(kp0 + 32);
    float4 c3 = ldnt4(kp0 + 36);
    const float* kp1 = kp0 + 16 * 64;
    float4 n0 = ldnt4(kp1);
    float4 n1 = ldnt4(kp1 + 4);
    float4 n2 = ldnt4(kp1 + 32);
    float4 n3 = ldnt4(kp1 + 36);

    const int len = __builtin_amdgcn_readfirstlane(keys_length[b]);

    // ---- fold W1: lane = (d2 = lane>>2 in 0..15, hg = lane&3) ----
    float cp0 = 0.f, cp1 = 0.f, cp2 = 0.f, cp3 = 0.f;
    {
        const int d2 = lane >> 2;
        const int hg = lane & 3;
        const float4* W1v = (const float4*)W1;   // [256][4] of float4
        #pragma unroll
        for (int dg = 0; dg < 4; dg++) {
            const int d = dg * 16 + d2;
            const float q = queries[b * 64 + d];
            float4 a  = W1v[(0   + d) * 4 + hg];
            float4 bb = W1v[(64  + d) * 4 + hg];
            float4 cc = W1v[(128 + d) * 4 + hg];
            float4 dd = W1v[(192 + d) * 4 + hg];
            float mv0 = bb.x - cc.x + q * dd.x;
            float mv1 = bb.y - cc.y + q * dd.y;
            float mv2 = bb.z - cc.z + q * dd.z;
            float mv3 = bb.w - cc.w + q * dd.w;
            cp0 += q * (a.x + cc.x);
            cp1 += q * (a.y + cc.y);
            cp2 += q * (a.z + cc.z);
            cp3 += q * (a.w + cc.w);
            const int hb = hg * 4;
            short h0 = f2bf(mv0), h1 = f2bf(mv1), h2 = f2bf(mv2), h3 = f2bf(mv3);
            MtHi[w][(hb + 0) * MTS + d] = h0;
            MtHi[w][(hb + 1) * MTS + d] = h1;
            MtHi[w][(hb + 2) * MTS + d] = h2;
            MtHi[w][(hb + 3) * MTS + d] = h3;
            MtLo[w][(hb + 0) * MTS + d] = f2bf(mv0 - bf2f(h0));
            MtLo[w][(hb + 1) * MTS + d] = f2bf(mv1 - bf2f(h1));
            MtLo[w][(hb + 2) * MTS + d] = f2bf(mv2 - bf2f(h2));
            MtLo[w][(hb + 3) * MTS + d] = f2bf(mv3 - bf2f(h3));
        }
        #pragma unroll
        for (int mask = 4; mask <= 32; mask <<= 1) {
            cp0 += __shfl_xor(cp0, mask, 64);
            cp1 += __shfl_xor(cp1, mask, 64);
            cp2 += __shfl_xor(cp2, mask, 64);
            cp3 += __shfl_xor(cp3, mask, 64);
        }
    }
    float cv4[4];
    cv4[0] = __shfl(cp0, quad, 64) + b1[quad * 4 + 0];
    cv4[1] = __shfl(cp1, quad, 64) + b1[quad * 4 + 1];
    cv4[2] = __shfl(cp2, quad, 64) + b1[quad * 4 + 2];
    cv4[3] = __shfl(cp3, quad, 64) + b1[quad * 4 + 3];

    // same-wave LDS write -> read (HW DS ops in-order per wave)
    asm volatile("" ::: "memory");
    __builtin_amdgcn_wave_barrier();

    // ---- scorer A-frags (Mt): A[row=h=m16][k=d=quad*8+j] ----
    const int bb0 = m16 * MTS + quad * 8;
    const bf16x8 Bh0 = *(const bf16x8*)&MtHi[w][bb0];
    const bf16x8 Bh1 = *(const bf16x8*)&MtHi[w][bb0 + 32];
    const bf16x8 Bl0 = *(const bf16x8*)&MtLo[w][bb0];
    const bf16x8 Bl1 = *(const bf16x8*)&MtLo[w][bb0 + 32];

    // ---- layer-2 A-frag: W2^T in scrambled-k order ----
    BF8 a2;
    {
        float w2f[4];
        #pragma unroll
        for (int j = 0; j < 4; j++)
            w2f[j] = (m16 < 8) ? W2[(quad * 4 + j) * 8 + m16] : 0.0f;
        a2.u[0] = cvtpk(w2f[0], w2f[1]);
        a2.u[1] = cvtpk(w2f[2], w2f[3]);
        a2.u[2] = 0u;
        a2.u[3] = 0u;
    }

    // ---- tiny operands ----
    const float4 b2a = *(const float4*)(b2);
    const float4 b2b = *(const float4*)(b2 + 4);
    const float4 w3a = *(const float4*)(W3);
    const float4 w3b = *(const float4*)(W3 + 4);
    const float  b3v = b3[0];
    const float b2k0 = quad == 0 ? b2a.x : (quad == 1 ? b2b.x : 0.f);
    const float b2k1 = quad == 0 ? b2a.y : (quad == 1 ? b2b.y : 0.f);
    const float b2k2 = quad == 0 ? b2a.z : (quad == 1 ? b2b.z : 0.f);
    const float b2k3 = quad == 0 ? b2a.w : (quad == 1 ? b2b.w : 0.f);
    const float w3k0 = quad == 0 ? w3a.x : (quad == 1 ? w3b.x : 0.f);
    const float w3k1 = quad == 0 ? w3a.y : (quad == 1 ? w3b.y : 0.f);
    const float w3k2 = quad == 0 ? w3a.z : (quad == 1 ? w3b.z : 0.f);
    const float w3k3 = quad == 0 ? w3a.w : (quad == 1 ? w3b.w : 0.f);

    // fixed softmax shift: |sc| <= 0.125*(|b3| + sum|W3|)
    const float M = 0.125f * (fabsf(b3v)
                  + fabsf(w3a.x) + fabsf(w3a.y) + fabsf(w3a.z) + fabsf(w3a.w)
                  + fabsf(w3b.x) + fabsf(w3b.y) + fabsf(w3b.z) + fabsf(w3b.w));

    // len==0: all positions masked in ref -> uniform softmax; sc=0.
    const int lenEff = (len == 0) ? TT : len;
    const int ntiles = (lenEff + 15) >> 4;

    float ssum = 0.0f;
    float o[16];
    #pragma unroll
    for (int j = 0; j < 16; j++) o[j] = 0.0f;

    const float4 z4 = {0.f, 0.f, 0.f, 0.f};
    // predicated streaming tile load (used from tile 2 on)
    #define LOADT(TL, A0, A1, A2, A3)                                   \
        { const int t_ = (TL) * 16 + m16;                               \
          if (t_ < lenEff) {                                            \
              const float* p_ = kb + t_ * 64 + quad * 8;                \
              A0 = ldnt4(p_);                                           \
              A1 = ldnt4(p_ + 4);                                       \
              A2 = ldnt4(p_ + 32);                                      \
              A3 = ldnt4(p_ + 36);                                      \
          } else { A0 = z4; A1 = z4; A2 = z4; A3 = z4; } }

    for (int tile = 0; tile < ntiles; tile++) {
        float4 m0, m1, m2, m3;
        LOADT(tile + 2, m0, m1, m2, m3);

        // keys -> bf16 (packed converts)
        BF8 ah0, ah1;
        ah0.u[0] = cvtpk(c0.x, c0.y);  ah0.u[1] = cvtpk(c0.z, c0.w);
        ah0.u[2] = cvtpk(c1.x, c1.y);  ah0.u[3] = cvtpk(c1.z, c1.w);
        ah1.u[0] = cvtpk(c2.x, c2.y);  ah1.u[1] = cvtpk(c2.z, c2.w);
        ah1.u[2] = cvtpk(c3.x, c3.y);  ah1.u[3] = cvtpk(c3.z, c3.w);

        // layer 1: D[h][t], lane holds t=m16, h=quad*4+r
        f32x4 acc = {0.f, 0.f, 0.f, 0.f};
        acc = __builtin_amdgcn_mfma_f32_16x16x32_bf16(Bh0, ah0.v, acc, 0, 0, 0);
        acc = __builtin_amdgcn_mfma_f32_16x16x32_bf16(Bl0, ah0.v, acc, 0, 0, 0);
        acc = __builtin_amdgcn_mfma_f32_16x16x32_bf16(Bh1, ah1.v, acc, 0, 0, 0);
        acc = __builtin_amdgcn_mfma_f32_16x16x32_bf16(Bl1, ah1.v, acc, 0, 0, 0);

        // sigmoid + pack h1 into scrambled-k B-frag (slots j>=4 zero)
        const float h10 = sigmoidf_(acc[0] + cv4[0]);
        const float h11 = sigmoidf_(acc[1] + cv4[1]);
        const float h12 = sigmoidf_(acc[2] + cv4[2]);
        const float h13 = sigmoidf_(acc[3] + cv4[3]);
        BF8 hb;
        hb.u[0] = cvtpk(h10, h11);
        hb.u[1] = cvtpk(h12, h13);
        hb.u[2] = 0u;
        hb.u[3] = 0u;

        // layer 2: D2[k][t]; lane holds k=quad*4+r
        f32x4 acc2 = {0.f, 0.f, 0.f, 0.f};
        acc2 = __builtin_amdgcn_mfma_f32_16x16x32_bf16(a2.v, hb.v, acc2, 0, 0, 0);

        // layer 3 partial over this lane's 4 k's, then cross-quad reduce
        float s3p;
        s3p = sigmoidf_(acc2[0] + b2k0) * w3k0;
        s3p = fmaf(sigmoidf_(acc2[1] + b2k1), w3k1, s3p);
        s3p = fmaf(sigmoidf_(acc2[2] + b2k2), w3k2, s3p);
        s3p = fmaf(sigmoidf_(acc2[3] + b2k3), w3k3, s3p);
        s3p += __shfl_xor(s3p, 16, 64);
        s3p += __shfl_xor(s3p, 32, 64);

        const int tg = tile * 16 + m16;
        float sc = (len == 0) ? 0.0f : (s3p + b3v) * 0.125f;  // / sqrt(64)
        if (tg >= lenEff) sc = -1.0e30f;                       // -> exp == 0
        const float p = __expf(sc - M);                        // <= 1

        ssum += p;
        o[0]  = fmaf(p, c0.x, o[0]);
        o[1]  = fmaf(p, c0.y, o[1]);
        o[2]  = fmaf(p, c0.z, o[2]);
        o[3]  = fmaf(p, c0.w, o[3]);
        o[4]  = fmaf(p, c1.x, o[4]);
        o[5]  = fmaf(p, c1.y, o[5]);
        o[6]  = fmaf(p, c1.z, o[6]);
        o[7]  = fmaf(p, c1.w, o[7]);
        o[8]  = fmaf(p, c2.x, o[8]);
        o[9]  = fmaf(p, c2.y, o[9]);
        o[10] = fmaf(p, c2.z, o[10]);
        o[11] = fmaf(p, c2.w, o[11]);
        o[12] = fmaf(p, c3.x, o[12]);
        o[13] = fmaf(p, c3.y, o[13]);
        o[14] = fmaf(p, c3.z, o[14]);
        o[15] = fmaf(p, c3.w, o[15]);

        c0 = n0; c1 = n1; c2 = n2; c3 = n3;
        n0 = m0; n1 = m1; n2 = m2; n3 = m3;
    }
    #undef LOADT

    // ---- final cross-t reduction (over m16 lanes) ----
    #pragma unroll
    for (int mask = 1; mask <= 8; mask <<= 1) {
        ssum += __shfl_xor(ssum, mask, 64);
        #pragma unroll
        for (int j = 0; j < 16; j++) o[j] += __shfl_xor(o[j], mask, 64);
    }
    const float inv = 1.0f / ssum;
    if (m16 == 0) {
        #pragma unroll
        for (int j = 0; j < 8; j++) vS[w][quad * 8 + j]      = o[j] * inv;
        #pragma unroll
        for (int j = 0; j < 8; j++) vS[w][32 + quad * 8 + j] = o[8 + j] * inv;
    }
    asm volatile("" ::: "memory");
    __builtin_amdgcn_wave_barrier();

    // ---- out[i=lane] = b4[i] + sum_d v[d] * W4[d][i] (W4 L2-hot) ----
    float po = b4[lane];
    const float4* vS4 = (const float4*)&vS[w][0];
    #pragma unroll 4
    for (int d0 = 0; d0 < 16; d0++) {
        const float4 vv = vS4[d0];
        const float* w4p = W4 + d0 * 256 + lane;
        po = fmaf(vv.x, w4p[0],   po);
        po = fmaf(vv.y, w4p[64],  po);
        po = fmaf(vv.z, w4p[128], po);
        po = fmaf(vv.w, w4p[192], po);
    }
    out[(size_t)b * 64 + lane] = po;
}

extern "C" void kernel_launch(void* const* d_in, const int* in_sizes, int n_in,
                              void* d_out, int out_size, void* d_ws, size_t ws_size,
                              hipStream_t stream) {
    const float* queries     = (const float*)d_in[0];
    const float* keys        = (const float*)d_in[1];
    const int*   keys_length = (const int*)  d_in[2];
    const float* W1 = (const float*)d_in[3];
    const float* b1 = (const float*)d_in[4];
    const float* W2 = (const float*)d_in[5];
    const float* b2 = (const float*)d_in[6];
    const float* W3 = (const float*)d_in[7];
    const float* b3 = (const float*)d_in[8];
    const float* W4 = (const float*)d_in[9];
    const float* b4 = (const float*)d_in[10];
    float* out = (float*)d_out;

    const int Bn = in_sizes[2];   // 4096
    const int blocks = (Bn + 3) >> 2;   // 4 rows per block (1 wave each)
    din_attn_flash<<<blocks, 256, 0, stream>>>(
        queries, keys, keys_length, W1, b1, W2, b2, W3, b3, W4, b4, out, Bn);
}

// Round 7
// 287.795 us; speedup vs baseline: 1.0666x; 1.0045x over previous
//
#include <hip/hip_runtime.h>
#include <math.h>

// Problem constants: B=4096, T=200, D=64
#define TT 200
#define MTS 72   // Mt row stride in bf16 elems (144 B rows: 16B-aligned)

typedef __attribute__((ext_vector_type(8))) short bf16x8;  // 8 bf16 = 4 VGPRs
typedef __attribute__((ext_vector_type(4))) float f32x4;
typedef __attribute__((ext_vector_type(4))) float fv4;     // native vec for builtins

union BF8 { bf16x8 v; unsigned u[4]; };
struct G { float4 v[4]; };   // one 16-row key tile slice per lane (coalesced layout)

__device__ __forceinline__ float sigmoidf_(float x) {
    return 1.0f / (1.0f + __expf(-x));
}
// packed f32->bf16 RNE convert (1 instr for 2 values)
__device__ __forceinline__ unsigned cvtpk(float a, float b) {
    unsigned r;
    asm("v_cvt_pk_bf16_f32 %0, %1, %2" : "=v"(r) : "v"(a), "v"(b));
    return r;
}
// scalar bf16 RNE (used only in the once-per-row W1 fold)
__device__ __forceinline__ short f2bf(float x) {
    unsigned u = __float_as_uint(x);
    u += 0x7fff + ((u >> 16) & 1);
    return (short)(u >> 16);
}
__device__ __forceinline__ float bf2f(short s) {
    return __uint_as_float(((unsigned)(unsigned short)s) << 16);
}
// streaming (non-temporal) float4 load: keys are read exactly once
__device__ __forceinline__ float4 ldnt4(const float* p) {
    fv4 t = __builtin_nontemporal_load((const fv4*)p);
    float4 r;
    r.x = t[0]; r.y = t[1]; r.z = t[2]; r.w = t[3];
    return r;
}

// One wave = one batch row; 4 waves per 256-thread block; static grid.
// Keys stream: fully-COALESCED 1KB loads (lane l <- bytes l*16 of the 4KB
// tile) -> cvtpk bf16 -> swizzled LDS tile -> ds_read_b128 MFMA fragments.
// 3-stage global pipeline (named-rotation, no dynamic reg indexing).
// o-accum uses the f32 coalesced registers (+4 p-shuffles) - full precision.
// Entry-prefetch of tiles 0/1 before keys_length; fixed-bound softmax;
// zero block barriers.
__global__ __launch_bounds__(256, 4) void din_attn_flash(
    const float* __restrict__ queries,     // [B,64]
    const float* __restrict__ keys,        // [B,200,64]
    const int*   __restrict__ keys_length, // [B]
    const float* __restrict__ W1,          // [256,16]
    const float* __restrict__ b1,          // [16]
    const float* __restrict__ W2,          // [16,8]
    const float* __restrict__ b2,          // [8]
    const float* __restrict__ W3,          // [8,1]
    const float* __restrict__ b3,          // [1]
    const float* __restrict__ W4,          // [64,64]
    const float* __restrict__ b4,          // [64]
    float* __restrict__ out,               // [B,64]
    int Bn)
{
    __shared__ __align__(16) short MtHi[4][16 * MTS];     // per-wave folded W1^T hi
    __shared__ __align__(16) short MtLo[4][16 * MTS];     // per-wave folded W1^T lo
    __shared__ __align__(16) unsigned short Kt[4][16 * 64]; // per-wave bf16 key tile (swizzled)
    __shared__ __align__(16) float vS[4][64];             // per-wave weighted key sum

    const int tid  = threadIdx.x;
    const int w    = tid >> 6;
    const int lane = tid & 63;
    const int m16  = lane & 15;
    const int quad = lane >> 4;

    const int b = blockIdx.x * 4 + w;
    if (b >= Bn) return;
    const float* kb = keys + (size_t)b * (TT * 64);
    char* ktb = (char*)&Kt[w][0];

    const float4 z4 = {0.f, 0.f, 0.f, 0.f};
    G g0, g1, g2;

    // ---- entry: issue tiles 0,1 COALESCED loads now (rows 0..31 < 200 always).
    // Instruction j covers floats [tile*1024 + j*256, +256): contiguous 1KB.
    {
        const float* tb = kb + lane * 4;
        #pragma unroll
        for (int j = 0; j < 4; j++) g0.v[j] = ldnt4(tb + j * 256);
        #pragma unroll
        for (int j = 0; j < 4; j++) g1.v[j] = ldnt4(tb + 1024 + j * 256);
    }

    const int len = __builtin_amdgcn_readfirstlane(keys_length[b]);

    // ---- fold W1: lane = (d2 = lane>>2 in 0..15, hg = lane&3) ----
    float cp0 = 0.f, cp1 = 0.f, cp2 = 0.f, cp3 = 0.f;
    {
        const int d2 = lane >> 2;
        const int hg = lane & 3;
        const float4* W1v = (const float4*)W1;   // [256][4] of float4
        #pragma unroll
        for (int dg = 0; dg < 4; dg++) {
            const int d = dg * 16 + d2;
            const float q = queries[b * 64 + d];
            float4 a  = W1v[(0   + d) * 4 + hg];
            float4 bb = W1v[(64  + d) * 4 + hg];
            float4 cc = W1v[(128 + d) * 4 + hg];
            float4 dd = W1v[(192 + d) * 4 + hg];
            float mv0 = bb.x - cc.x + q * dd.x;
            float mv1 = bb.y - cc.y + q * dd.y;
            float mv2 = bb.z - cc.z + q * dd.z;
            float mv3 = bb.w - cc.w + q * dd.w;
            cp0 += q * (a.x + cc.x);
            cp1 += q * (a.y + cc.y);
            cp2 += q * (a.z + cc.z);
            cp3 += q * (a.w + cc.w);
            const int hb = hg * 4;
            short h0 = f2bf(mv0), h1 = f2bf(mv1), h2 = f2bf(mv2), h3 = f2bf(mv3);
            MtHi[w][(hb + 0) * MTS + d] = h0;
            MtHi[w][(hb + 1) * MTS + d] = h1;
            MtHi[w][(hb + 2) * MTS + d] = h2;
            MtHi[w][(hb + 3) * MTS + d] = h3;
            MtLo[w][(hb + 0) * MTS + d] = f2bf(mv0 - bf2f(h0));
            MtLo[w][(hb + 1) * MTS + d] = f2bf(mv1 - bf2f(h1));
            MtLo[w][(hb + 2) * MTS + d] = f2bf(mv2 - bf2f(h2));
            MtLo[w][(hb + 3) * MTS + d] = f2bf(mv3 - bf2f(h3));
        }
        #pragma unroll
        for (int mask = 4; mask <= 32; mask <<= 1) {
            cp0 += __shfl_xor(cp0, mask, 64);
            cp1 += __shfl_xor(cp1, mask, 64);
            cp2 += __shfl_xor(cp2, mask, 64);
            cp3 += __shfl_xor(cp3, mask, 64);
        }
    }
    float cv4[4];
    cv4[0] = __shfl(cp0, quad, 64) + b1[quad * 4 + 0];
    cv4[1] = __shfl(cp1, quad, 64) + b1[quad * 4 + 1];
    cv4[2] = __shfl(cp2, quad, 64) + b1[quad * 4 + 2];
    cv4[3] = __shfl(cp3, quad, 64) + b1[quad * 4 + 3];

    // same-wave LDS write -> read (HW DS ops in-order per wave)
    asm volatile("" ::: "memory");
    __builtin_amdgcn_wave_barrier();

    // ---- scorer A-frags (Mt): A[row=h=m16][k=d=quad*8+j] ----
    const int bb0 = m16 * MTS + quad * 8;
    const bf16x8 Bh0 = *(const bf16x8*)&MtHi[w][bb0];
    const bf16x8 Bh1 = *(const bf16x8*)&MtHi[w][bb0 + 32];
    const bf16x8 Bl0 = *(const bf16x8*)&MtLo[w][bb0];
    const bf16x8 Bl1 = *(const bf16x8*)&MtLo[w][bb0 + 32];

    // ---- layer-2 A-frag: W2^T in scrambled-k order ----
    BF8 a2;
    {
        float w2f[4];
        #pragma unroll
        for (int j = 0; j < 4; j++)
            w2f[j] = (m16 < 8) ? W2[(quad * 4 + j) * 8 + m16] : 0.0f;
        a2.u[0] = cvtpk(w2f[0], w2f[1]);
        a2.u[1] = cvtpk(w2f[2], w2f[3]);
        a2.u[2] = 0u;
        a2.u[3] = 0u;
    }

    // ---- tiny operands ----
    const float4 b2a = *(const float4*)(b2);
    const float4 b2b = *(const float4*)(b2 + 4);
    const float4 w3a = *(const float4*)(W3);
    const float4 w3b = *(const float4*)(W3 + 4);
    const float  b3v = b3[0];
    const float b2k0 = quad == 0 ? b2a.x : (quad == 1 ? b2b.x : 0.f);
    const float b2k1 = quad == 0 ? b2a.y : (quad == 1 ? b2b.y : 0.f);
    const float b2k2 = quad == 0 ? b2a.z : (quad == 1 ? b2b.z : 0.f);
    const float b2k3 = quad == 0 ? b2a.w : (quad == 1 ? b2b.w : 0.f);
    const float w3k0 = quad == 0 ? w3a.x : (quad == 1 ? w3b.x : 0.f);
    const float w3k1 = quad == 0 ? w3a.y : (quad == 1 ? w3b.y : 0.f);
    const float w3k2 = quad == 0 ? w3a.z : (quad == 1 ? w3b.z : 0.f);
    const float w3k3 = quad == 0 ? w3a.w : (quad == 1 ? w3b.w : 0.f);

    // fixed softmax shift: |sc| <= 0.125*(|b3| + sum|W3|)
    const float M = 0.125f * (fabsf(b3v)
                  + fabsf(w3a.x) + fabsf(w3a.y) + fabsf(w3a.z) + fabsf(w3a.w)
                  + fabsf(w3b.x) + fabsf(w3b.y) + fabsf(w3b.z) + fabsf(w3b.w));

    // len==0: all positions masked in ref -> uniform softmax; sc=0.
    const int lenEff = (len == 0) ? TT : len;
    const int ntiles = (lenEff + 15) >> 4;

    float ssum = 0.0f;
    float4 o4 = z4;   // partial out for cols m16*4..+3, rows == quad (mod 4 groups)

    // cvt + swizzled LDS write of one tile from G-regs.
    // Lane holds rows j*4+quad, cols m16*4..+3 -> byte (row*128 + swz(m16*8)).
    #define CVTW(SRC)                                                        \
        { _Pragma("unroll")                                                  \
          for (int j = 0; j < 4; j++) {                                      \
              const int row_ = j * 4 + quad;                                 \
              uint2 val_;                                                    \
              val_.x = cvtpk(SRC.v[j].x, SRC.v[j].y);                        \
              val_.y = cvtpk(SRC.v[j].z, SRC.v[j].w);                        \
              *(uint2*)(ktb + row_ * 128 + ((m16 * 8) ^ ((row_ & 7) << 4)))  \
                  = val_;                                                    \
          } }

    // fragment read: lane (m16,quad) <- row m16, cols quad*8..+7 (ah0) and
    // 32+quad*8..+7 (ah1). Swizzle is XOR-linear so ah1 addr = ah0 addr ^ 64.
    #define FRD()                                                            \
        { asm volatile("" ::: "memory");                                     \
          const int offr_ = m16 * 128 + ((quad * 16) ^ ((m16 & 7) << 4));    \
          ah0 = *(const bf16x8*)(ktb + offr_);                               \
          ah1 = *(const bf16x8*)(ktb + (offr_ ^ 64));                        \
          asm volatile("" ::: "memory"); }

    bf16x8 ah0, ah1;

    // prologue: stage tile 0 into LDS, read its fragments
    CVTW(g0)
    FRD()

    // BODY(IN=tile i regs, MID=tile i+1 regs, FAR=dest for tile i+2, TI=i)
    #define BODY(IN, MID, FAR, TI)                                           \
    {                                                                        \
        /* 1. issue coalesced loads tile TI+2 (predicated by lenEff) */      \
        { const int TL_ = (TI) + 2;                                          \
          const float* tb_ = kb + TL_ * 1024 + lane * 4;                     \
          _Pragma("unroll")                                                  \
          for (int j = 0; j < 4; j++) {                                      \
              const int row_ = TL_ * 16 + j * 4 + quad;                      \
              FAR.v[j] = (row_ < lenEff) ? ldnt4(tb_ + j * 256) : z4;        \
          } }                                                                \
        /* 2. cvt + LDS-write tile TI+1 (vmcnt waits on MID) */              \
        CVTW(MID)                                                            \
        /* 3. scores for tile TI from fragments */                           \
        f32x4 acc = {0.f, 0.f, 0.f, 0.f};                                    \
        acc = __builtin_amdgcn_mfma_f32_16x16x32_bf16(Bh0, ah0, acc, 0,0,0); \
        acc = __builtin_amdgcn_mfma_f32_16x16x32_bf16(Bl0, ah0, acc, 0,0,0); \
        acc = __builtin_amdgcn_mfma_f32_16x16x32_bf16(Bh1, ah1, acc, 0,0,0); \
        acc = __builtin_amdgcn_mfma_f32_16x16x32_bf16(Bl1, ah1, acc, 0,0,0); \
        const float h10 = sigmoidf_(acc[0] + cv4[0]);                        \
        const float h11 = sigmoidf_(acc[1] + cv4[1]);                        \
        const float h12 = sigmoidf_(acc[2] + cv4[2]);                        \
        const float h13 = sigmoidf_(acc[3] + cv4[3]);                        \
        BF8 hb;                                                              \
        hb.u[0] = cvtpk(h10, h11);                                           \
        hb.u[1] = cvtpk(h12, h13);                                           \
        hb.u[2] = 0u;                                                        \
        hb.u[3] = 0u;                                                        \
        f32x4 acc2 = {0.f, 0.f, 0.f, 0.f};                                   \
        acc2 = __builtin_amdgcn_mfma_f32_16x16x32_bf16(a2.v, hb.v, acc2, 0,0,0); \
        float s3p;                                                           \
        s3p = sigmoidf_(acc2[0] + b2k0) * w3k0;                              \
        s3p = fmaf(sigmoidf_(acc2[1] + b2k1), w3k1, s3p);                    \
        s3p = fmaf(sigmoidf_(acc2[2] + b2k2), w3k2, s3p);                    \
        s3p = fmaf(sigmoidf_(acc2[3] + b2k3), w3k3, s3p);                    \
        s3p += __shfl_xor(s3p, 16, 64);                                      \
        s3p += __shfl_xor(s3p, 32, 64);                                      \
        const int tg_ = (TI) * 16 + m16;                                     \
        float sc = (len == 0) ? 0.0f : (s3p + b3v) * 0.125f;                 \
        if (tg_ >= lenEff) sc = -1.0e30f;                                    \
        const float p = __expf(sc - M);                                      \
        ssum += p;                                                           \
        /* 4. o-accum from f32 IN regs: pj = p of row (TI*16 + j*4+quad) */  \
        _Pragma("unroll")                                                    \
        for (int j = 0; j < 4; j++) {                                        \
            const float pj = __shfl(p, j * 4 + quad, 64);                    \
            o4.x = fmaf(pj, IN.v[j].x, o4.x);                                \
            o4.y = fmaf(pj, IN.v[j].y, o4.y);                                \
            o4.z = fmaf(pj, IN.v[j].z, o4.z);                                \
            o4.w = fmaf(pj, IN.v[j].w, o4.w);                                \
        }                                                                    \
        /* 5. fragments for tile TI+1 */                                     \
        FRD()                                                                \
    }

    int i = 0;
    while (true) {
        BODY(g0, g1, g2, i) if (++i >= ntiles) break;
        BODY(g1, g2, g0, i) if (++i >= ntiles) break;
        BODY(g2, g0, g1, i) if (++i >= ntiles) break;
    }
    #undef BODY
    #undef CVTW
    #undef FRD

    // ---- final reductions ----
    // ssum: identical across quads; sum over 16 t's (m16 bits)
    ssum += __shfl_xor(ssum, 1, 64);
    ssum += __shfl_xor(ssum, 2, 64);
    ssum += __shfl_xor(ssum, 4, 64);
    ssum += __shfl_xor(ssum, 8, 64);
    // o4: sum across quads (each quad covered rows == quad mod 4)
    o4.x += __shfl_xor(o4.x, 16, 64);  o4.x += __shfl_xor(o4.x, 32, 64);
    o4.y += __shfl_xor(o4.y, 16, 64);  o4.y += __shfl_xor(o4.y, 32, 64);
    o4.z += __shfl_xor(o4.z, 16, 64);  o4.z += __shfl_xor(o4.z, 32, 64);
    o4.w += __shfl_xor(o4.w, 16, 64);  o4.w += __shfl_xor(o4.w, 32, 64);

    const float inv = 1.0f / ssum;
    if (lane < 16) {
        float4 t;
        t.x = o4.x * inv; t.y = o4.y * inv; t.z = o4.z * inv; t.w = o4.w * inv;
        *(float4*)&vS[w][lane * 4] = t;
    }
    asm volatile("" ::: "memory");
    __builtin_amdgcn_wave_barrier();

    // ---- out[i=lane] = b4[i] + sum_d v[d] * W4[d][i] (W4 L2-hot) ----
    float po = b4[lane];
    const float4* vS4 = (const float4*)&vS[w][0];
    #pragma unroll 4
    for (int d0 = 0; d0 < 16; d0++) {
        const float4 vv = vS4[d0];
        const float* w4p = W4 + d0 * 256 + lane;
        po = fmaf(vv.x, w4p[0],   po);
        po = fmaf(vv.y, w4p[64],  po);
        po = fmaf(vv.z, w4p[128], po);
        po = fmaf(vv.w, w4p[192], po);
    }
    out[(size_t)b * 64 + lane] = po;
}

extern "C" void kernel_launch(void* const* d_in, const int* in_sizes, int n_in,
                              void* d_out, int out_size, void* d_ws, size_t ws_size,
                              hipStream_t stream) {
    const float* queries     = (const float*)d_in[0];
    const float* keys        = (const float*)d_in[1];
    const int*   keys_length = (const int*)  d_in[2];
    const float* W1 = (const float*)d_in[3];
    const float* b1 = (const float*)d_in[4];
    const float* W2 = (const float*)d_in[5];
    const float* b2 = (const float*)d_in[6];
    const float* W3 = (const float*)d_in[7];
    const float* b3 = (const float*)d_in[8];
    const float* W4 = (const float*)d_in[9];
    const float* b4 = (const float*)d_in[10];
    float* out = (float*)d_out;

    const int Bn = in_sizes[2];   // 4096
    const int blocks = (Bn + 3) >> 2;   // 4 rows per block (1 wave each)
    din_attn_flash<<<blocks, 256, 0, stream>>>(
        queries, keys, keys_length, W1, b1, W2, b2, W3, b3, W4, b4, out, Bn);
}